// Round 17
// baseline (139.171 us; speedup 1.0000x reference)
//
#include <hip/hip_runtime.h>
#include <hip/hip_bf16.h>

// Problem constants: B=2, S=2048, D=1024, H=16, HD=64, M = B*S = 4096

typedef __attribute__((ext_vector_type(8))) short short8;    // 8 bf16 = 4 VGPR
typedef __attribute__((ext_vector_type(4))) short short4v;   // 4 bf16
typedef __attribute__((ext_vector_type(4))) float f32x4;     // 16x16 C/D frag

static __device__ __forceinline__ short f2bf(float f) {
    union { float f; unsigned u; } c; c.f = f;
    unsigned r = c.u + 0x7fff + ((c.u >> 16) & 1);   // RNE
    return (short)(r >> 16);
}

// packed f32x2 -> bf16x2 (v_cvt_pk_bf16_f32)
static __device__ __forceinline__ unsigned pk_bf16(float a, float b) {
    union { __hip_bfloat162 h; unsigned u; } c;
    c.h = __float22bfloat162_rn(make_float2(a, b));
    return c.u;
}

// async global -> LDS, 16B per lane (global_load_lds_dwordx4).
typedef const void __attribute__((address_space(1)))* gas_ptr;
typedef void __attribute__((address_space(3)))* las_ptr;
static __device__ __forceinline__ void gload16(const void* g, void* l) {
    __builtin_amdgcn_global_load_lds((gas_ptr)g, (las_ptr)l, 16, 0, 0);
}

// ---------------------------------------------------------------------------
// prep: weight transpose only (4 x W[K][N] f32 -> Wt[N][K] bf16), 4096 blocks.
// (tobf16 of the activations is now fused into gemmqkv's A staging — the r9
// re-fetch pathology is fixed by the XCD-chunked remap: all 8 n-tiles of an
// A-panel are consecutive in one XCD's 96-block chunk = exactly co-resident.)
// ---------------------------------------------------------------------------
__global__ __launch_bounds__(256) void prep(
    const float* __restrict__ W0, const float* __restrict__ W1,
    const float* __restrict__ W2, const float* __restrict__ W3,
    short* __restrict__ Wt)
{
    __shared__ float tile[32][33];
    const int wid = blockIdx.x;
    const int z = wid >> 10;
    const float* W = z == 0 ? W0 : z == 1 ? W1 : z == 2 ? W2 : W3;
    short* O = Wt + ((size_t)z << 20);
    const int k0 = (wid & 31) * 32, n0 = ((wid >> 5) & 31) * 32;
    const int tx = threadIdx.x & 31, ty = threadIdx.x >> 5;  // (32,8)
    #pragma unroll
    for (int j = 0; j < 32; j += 8)
        tile[ty + j][tx] = W[(k0 + ty + j) * 1024 + n0 + tx];
    __syncthreads();
    #pragma unroll
    for (int j = 0; j < 32; j += 8)
        O[(n0 + ty + j) * 1024 + k0 + tx] = f2bf(tile[tx][ty + j]);
}

// ---------------------------------------------------------------------------
// Merged Q/K/V projection GEMM, 128x128 tile, FUSED f32->bf16 A conversion.
// BM=BN=128, BK=32, 4 waves x (64x64 quadrant, acc[4][4] of 16x16x32).
// B (bf16 weights) staged via global_load_lds dwordx4. A (f32 activations)
// reg-staged: 4x float4 issued at top of K-step (T14), cvt_pk + 2 lane-linear
// ds_write_b128 after the MFMA cluster (LDS off j*2048+t*8 == row*32+kc*8,
// conflict-free). T1 XCD chunking: remap=(flat&7)*96+flat>>3 (768%8==0) ->
// the 8 n-tiles sharing an A-panel are consecutive within one XCD's chunk,
// and 96 blocks/chunk = 3/CU x 32 CU co-resident -> A-panel HBM-read once,
// 7x L2 hits. Grid (8,32,3) = 768 blocks.
// ---------------------------------------------------------------------------
__global__ __launch_bounds__(256, 3) void gemmqkv(
    const float* __restrict__ Xq, const float* __restrict__ Xk,
    const float* __restrict__ Xv, const short* __restrict__ Wt,
    const float* __restrict__ bq, const float* __restrict__ bk,
    const float* __restrict__ bv, short* __restrict__ Qh,
    short* __restrict__ Kh, short* __restrict__ Vt, float qscale)
{
    __shared__ short Al[2][4096];   // [128 m][32 k] bf16 (converted in-kernel)
    __shared__ short Bl[2][4096];   // [128 n][32 k] bf16
    const int flat = blockIdx.z * 256 + blockIdx.y * 8 + blockIdx.x;
    const int remap = (flat & 7) * 96 + (flat >> 3);   // 768 % 8 == 0: bijective
    const int z = remap >> 8;
    const int rem = remap & 255;
    const int m0 = (rem >> 3) * 128, n0 = (rem & 7) * 128;

    const float* Af = z == 0 ? Xq : z == 1 ? Xk : Xv;
    const short* Ba = Wt + ((size_t)z << 20);
    const float* bias = z == 0 ? bq : z == 1 ? bk : bv;
    short* O = z == 0 ? Qh : z == 1 ? Kh : Vt;
    const float scale = z == 0 ? qscale : 1.0f;

    const int t = threadIdx.x;
    const int lane = t & 63, w = t >> 6;
    const int lm = lane & 15, lg = lane >> 4;
    const int wr = w >> 1, wc = w & 1;

    // A chunks: c = j*256 + t -> row c>>2, k-chunk c&3; LDS dest j*2048 + t*8
    const float* Ag0 = Af + (size_t)(m0 + (t >> 2)) * 1024 + (t & 3) * 8;
    const float* Ag1 = Ag0 + (size_t)64 * 1024;
    short* const ad0[2] = { &Al[0][t * 8],        &Al[1][t * 8]        };
    short* const ad1[2] = { &Al[0][2048 + t * 8], &Al[1][2048 + t * 8] };

    #define STAGEB(buf, k0) do {                                              \
        _Pragma("unroll")                                                     \
        for (int j = 0; j < 2; ++j) {                                         \
            const int c = j * 256 + t;                                        \
            gload16(Ba + (size_t)(n0 + (c >> 2)) * 1024 + (k0) + (c & 3) * 8, \
                    &Bl[buf][j * 2048 + w * 512]);                            \
        }                                                                     \
    } while (0)
    #define CVT8(dst, va, vb) do {                                            \
        uint4 r_;                                                             \
        r_.x = pk_bf16((va).x, (va).y); r_.y = pk_bf16((va).z, (va).w);       \
        r_.z = pk_bf16((vb).x, (vb).y); r_.w = pk_bf16((vb).z, (vb).w);       \
        *(uint4*)(dst) = r_;                                                  \
    } while (0)

    f32x4 acc[4][4] = {};

    {   // prologue: tile 0
        float4 a00 = *(const float4*)(Ag0);
        float4 a01 = *(const float4*)(Ag0 + 4);
        float4 a10 = *(const float4*)(Ag1);
        float4 a11 = *(const float4*)(Ag1 + 4);
        STAGEB(0, 0);
        CVT8(ad0[0], a00, a01);
        CVT8(ad1[0], a10, a11);
    }
    __syncthreads();

    int buf = 0;
    for (int kk = 0; kk < 32; ++kk) {
        float4 a00, a01, a10, a11;
        const bool pfn = (kk < 31);
        if (pfn) {
            const int kn = (kk + 1) * 32;
            a00 = *(const float4*)(Ag0 + kn);
            a01 = *(const float4*)(Ag0 + kn + 4);
            a10 = *(const float4*)(Ag1 + kn);
            a11 = *(const float4*)(Ag1 + kn + 4);
            STAGEB(buf ^ 1, kn);
        }

        const short* Ab = Al[buf];
        const short* Bb = Bl[buf];
        short8 af[4], bfr[4];
        #pragma unroll
        for (int mf = 0; mf < 4; ++mf)
            af[mf] = *(const short8*)(Ab + (wr * 64 + mf * 16 + lm) * 32 + lg * 8);
        #pragma unroll
        for (int nf = 0; nf < 4; ++nf)
            bfr[nf] = *(const short8*)(Bb + (wc * 64 + nf * 16 + lm) * 32 + lg * 8);
        #pragma unroll
        for (int mf = 0; mf < 4; ++mf)
            #pragma unroll
            for (int nf = 0; nf < 4; ++nf)
                acc[mf][nf] = __builtin_amdgcn_mfma_f32_16x16x32_bf16(
                    af[mf], bfr[nf], acc[mf][nf], 0, 0, 0);

        if (pfn) {
            CVT8(ad0[buf ^ 1], a00, a01);
            CVT8(ad1[buf ^ 1], a10, a11);
        }
        __syncthreads();
        buf ^= 1;
    }
    #undef STAGEB
    #undef CVT8

    // epilogue — D frag: col = lm (n), rows = lg*4 + i (m)
    #pragma unroll
    for (int mf = 0; mf < 4; ++mf) {
        const int mb = m0 + wr * 64 + mf * 16 + lg * 4;
        #pragma unroll
        for (int nf = 0; nf < 4; ++nf) {
            const int n = n0 + wc * 64 + nf * 16 + lm;
            const float bs = bias[n];
            if (z == 2) {   // V^T [B,H,64,S]: 4 consecutive s per lane
                short4v sv;
                #pragma unroll
                for (int i = 0; i < 4; ++i)
                    sv[i] = f2bf(acc[mf][nf][i] + bs);
                const int addr = (((mb >> 11) * 16 + (n >> 6)) * 64 + (n & 63)) * 2048 + (mb & 2047);
                *(short4v*)&O[addr] = sv;
            } else {        // head-split [B,H,S,64]
                #pragma unroll
                for (int i = 0; i < 4; ++i) {
                    const int m = mb + i;
                    const int addr = (((m >> 11) * 16 + (n >> 6)) * 2048 + (m & 2047)) * 64 + (n & 63);
                    O[addr] = f2bf(scale * (acc[mf][nf][i] + bs));
                }
            }
        }
    }
}

// ---------------------------------------------------------------------------
// GEMM core (BM=64, BN=128, BK=32), 4 waves — kept for gemmo (512 blocks =
// 2/CU; a 128^2 gemmo would be 256 blocks = 1/CU, the r4 starvation regime).
// ---------------------------------------------------------------------------
#define STAGE(buf, k0) do {                                                   \
    gload16(Aa + (size_t)(gm0 + (t >> 2)) * 1024 + (k0) + (t & 3) * 8,        \
            &Al[buf][w * 512]);                                               \
    _Pragma("unroll")                                                         \
    for (int j = 0; j < 2; ++j) {                                             \
        const int c = j * 256 + t;                                            \
        gload16(Ba + (size_t)(gn0 + (c >> 2)) * 1024 + (k0) + (c & 3) * 8,    \
                &Bl[buf][j * 2048 + w * 512]);                                \
    }                                                                         \
} while (0)

#define GEMM_CORE(Aa_, Ba_, m0v, n0v)                                         \
    __shared__ short Al[2][2048];   /* [64 m][32 k] */                        \
    __shared__ short Bl[2][4096];   /* [128 n][32 k] */                       \
    const int t = threadIdx.x;                                                \
    const int gm0 = (m0v), gn0 = (n0v);                                       \
    const int lane = t & 63, w = t >> 6;                                      \
    const int lm = lane & 15, lg = lane >> 4;                                 \
    const int wr = w >> 1, wc = w & 1;                                        \
    f32x4 acc[2][4] = {};                                                     \
    STAGE(0, 0);                                                              \
    __syncthreads();                                                          \
    int buf = 0;                                                              \
    for (int kk = 0; kk < 32; ++kk) {                                         \
        if (kk < 31) STAGE(buf ^ 1, (kk + 1) * 32);                           \
        const short* Ab = Al[buf];                                            \
        const short* Bb = Bl[buf];                                            \
        short8 af[2], bfr[4];                                                 \
        _Pragma("unroll")                                                     \
        for (int mf = 0; mf < 2; ++mf)                                        \
            af[mf] = *(const short8*)(Ab + (wr * 32 + mf * 16 + lm) * 32 + lg * 8); \
        _Pragma("unroll")                                                     \
        for (int nf = 0; nf < 4; ++nf)                                        \
            bfr[nf] = *(const short8*)(Bb + (wc * 64 + nf * 16 + lm) * 32 + lg * 8); \
        _Pragma("unroll")                                                     \
        for (int mf = 0; mf < 2; ++mf)                                        \
            _Pragma("unroll")                                                 \
            for (int nf = 0; nf < 4; ++nf)                                    \
                acc[mf][nf] = __builtin_amdgcn_mfma_f32_16x16x32_bf16(        \
                    af[mf], bfr[nf], acc[mf][nf], 0, 0, 0);                   \
        __syncthreads();                                                      \
        buf ^= 1;                                                             \
    }

// ---------------------------------------------------------------------------
// Final projection: out = Ctx @ Wo^T + bo, f32 flat. 512 blocks, XCD swizzle.
// ---------------------------------------------------------------------------
__global__ __launch_bounds__(256) void gemmo(
    const short* __restrict__ Aa, const short* __restrict__ Ba,
    const float* __restrict__ bias, float* __restrict__ Out)
{
    const int flat = blockIdx.y * 8 + blockIdx.x;
    const int remap = (flat & 7) * 64 + (flat >> 3);    // 512 % 8 == 0: bijective
    const int m0 = (remap >> 3) * 64, n0 = (remap & 7) * 128;

    GEMM_CORE(Aa, Ba, m0, n0)

    #pragma unroll
    for (int mf = 0; mf < 2; ++mf) {
        const int mb = m0 + wr * 32 + mf * 16 + lg * 4;
        #pragma unroll
        for (int nf = 0; nf < 4; ++nf) {
            const int n = n0 + wc * 64 + nf * 16 + lm;
            const float bs = bias[n];
            #pragma unroll
            for (int i = 0; i < 4; ++i)
                Out[(mb + i) * 1024 + n] = acc[mf][nf][i] + bs;
        }
    }
}
#undef STAGE
#undef GEMM_CORE

// ---------------------------------------------------------------------------
// Flash attention v12 (unchanged; best measured ~74 µs, FETCH 12 MB):
// 8 waves x 16 q-rows, KVBLK=128/barrier, V tile as two [64][64] halves,
// XOR chunk swizzle, double-buffer + T14, 1 barrier/tile, swapped QK^T/PV,
// exp2 softmax, defer-max, tree reductions, XCD-chunked remap. LDS 80KB.
// ---------------------------------------------------------------------------
__global__ __launch_bounds__(512, 4) void attn_k(
    const short* __restrict__ Q, const short* __restrict__ K,
    const short* __restrict__ V, short* __restrict__ Ctx)
{
    __shared__ short Kl[2][128][64];
    __shared__ short Vl[2][2][64][64];   // [buf][key-half][d-row][key-chunk]
    __shared__ short Pl[8][16][64];
    const int t = threadIdx.x;
    const int flat = blockIdx.y * 16 + blockIdx.x;
    const int remap = (flat & 7) * 64 + (flat >> 3);   // 512 % 8 == 0: bijective
    const int qt = remap & 15, bh = remap >> 4;        // XCD c -> bh in [4c,4c+4)
    const int lane = t & 63, w = t >> 6;   // 8 waves
    const int lm = lane & 15, lg = lane >> 4;
    const int swz = (lm & 7) << 3;          // P-buffer swizzle (shorts)
    const int swc = lm & 7;                 // K/V read chunk swizzle

    const int qrow = qt * 128 + w * 16 + lm;
    short8 qf[2];
    #pragma unroll
    for (int ks = 0; ks < 2; ++ks)
        qf[ks] = *(const short8*)(Q + ((size_t)bh * 2048 + qrow) * 64 + ks * 32 + lg * 8);

    float m_run = -3e38f, l_run = 0.f;
    f32x4 o_acc[4] = {};

    const int rk = t >> 2, ck = t & 3;
    const int rv = t >> 3, cv = t & 7;
    const short* Kg = K + ((size_t)bh * 2048 + rk) * 64 + ck * 16;
    const short* Vg = V + ((size_t)bh * 64 + rv) * 2048 + cv * 16;
    const int koff0 = rk * 64 + ((ck * 2) ^ (rk & 7)) * 8;
    const int koff1 = rk * 64 + ((ck * 2 + 1) ^ (rk & 7)) * 8;
    const int vhalf = (cv >> 2) * 4096;
    const int voff0 = vhalf + rv * 64 + (((cv * 2) & 7) ^ (rv & 7)) * 8;
    const int voff1 = vhalf + rv * 64 + (((cv * 2 + 1) & 7) ^ (rv & 7)) * 8;

    {   // prologue: stage tile 0 into buffer 0
        short8 a = *(const short8*)(Kg);
        short8 b = *(const short8*)(Kg + 8);
        short8 c = *(const short8*)(Vg);
        short8 d = *(const short8*)(Vg + 8);
        *(short8*)((short*)Kl[0] + koff0) = a;
        *(short8*)((short*)Kl[0] + koff1) = b;
        *(short8*)((short*)Vl[0] + voff0) = c;
        *(short8*)((short*)Vl[0] + voff1) = d;
    }

    short* prow = &Pl[w][lm][0];
    int cur = 0;

    for (int kt = 0; kt < 16; ++kt) {
        __syncthreads();   // stage[cur] visible; [cur^1] free for writing

        // early-issue global loads for tile kt+1 (T14)
        short8 kn0, kn1, vn0, vn1;
        const bool pfn = (kt < 15);
        if (pfn) {
            const short* Kgn = Kg + (size_t)(kt + 1) * 8192;   // 128 rows * 64
            const short* Vgn = Vg + (kt + 1) * 128;
            kn0 = *(const short8*)(Kgn);
            kn1 = *(const short8*)(Kgn + 8);
            vn0 = *(const short8*)(Vgn);
            vn1 = *(const short8*)(Vgn + 8);
        }

        const short* Kc = (const short*)Kl[cur];
        const short* Vc = (const short*)Vl[cur];

        // ---- S^T = K Q^T, BOTH halves: lane holds q=lm, 32 key-vals ----
        f32x4 sa[2][4] = {};
        #pragma unroll
        for (int h = 0; h < 2; ++h)
            #pragma unroll
            for (int nf = 0; nf < 4; ++nf) {
                const int rr = h * 64 + nf * 16 + lm;
                #pragma unroll
                for (int ks = 0; ks < 2; ++ks) {
                    const short8 kf = *(const short8*)(Kc + rr * 64 + ((ks * 4 + lg) ^ swc) * 8);
                    sa[h][nf] = __builtin_amdgcn_mfma_f32_16x16x32_bf16(kf, qf[ks], sa[h][nf], 0, 0, 0);
                }
            }

        // ---- max reduce: pairwise tree (fmaxf nests fuse to v_max3) ----
        float mx[8];
        #pragma unroll
        for (int h = 0; h < 2; ++h)
            #pragma unroll
            for (int nf = 0; nf < 4; ++nf) {
                const f32x4 v = sa[h][nf];
                mx[h * 4 + nf] = fmaxf(fmaxf(v[0], v[1]), fmaxf(v[2], v[3]));
            }
        float mt = fmaxf(fmaxf(fmaxf(mx[0], mx[1]), fmaxf(mx[2], mx[3])),
                         fmaxf(fmaxf(mx[4], mx[5]), fmaxf(mx[6], mx[7])));
        mt = fmaxf(mt, __shfl_xor(mt, 16));
        mt = fmaxf(mt, __shfl_xor(mt, 32));
        if (__any(mt > m_run + 8.0f)) {     // defer-max (T13)
            const float mn = fmaxf(m_run, mt);
            const float alpha = exp2f(m_run - mn);
            l_run *= alpha;
            #pragma unroll
            for (int nf = 0; nf < 4; ++nf)
                #pragma unroll
                for (int i = 0; i < 4; ++i)
                    o_acc[nf][i] *= alpha;
            m_run = mn;
        }
        // exp2 + tree-structured sum (8 frag-partials -> 3-level tree)
        float ps[8];
        #pragma unroll
        for (int h = 0; h < 2; ++h)
            #pragma unroll
            for (int nf = 0; nf < 4; ++nf) {
                f32x4 v = sa[h][nf];
                #pragma unroll
                for (int i = 0; i < 4; ++i) v[i] = exp2f(v[i] - m_run);
                sa[h][nf] = v;
                ps[h * 4 + nf] = (v[0] + v[1]) + (v[2] + v[3]);
            }
        float rs = ((ps[0] + ps[1]) + (ps[2] + ps[3])) +
                   ((ps[4] + ps[5]) + (ps[6] + ps[7]));
        rs += __shfl_xor(rs, 16);
        rs += __shfl_xor(rs, 32);
        l_run += rs;

        // ---- per key-half: P-pack -> pf -> PV (P buffer reused) ----
        #pragma unroll
        for (int h = 0; h < 2; ++h) {
            #pragma unroll
            for (int nf = 0; nf < 4; ++nf) {
                uint2 pv;
                pv.x = pk_bf16(sa[h][nf][0], sa[h][nf][1]);
                pv.y = pk_bf16(sa[h][nf][2], sa[h][nf][3]);
                *(uint2*)(prow + ((nf * 16 + lg * 4) ^ swz)) = pv;
            }
            short8 pf[2];
            #pragma unroll
            for (int ks = 0; ks < 2; ++ks)
                pf[ks] = *(const short8*)(prow + ((ks * 32 + lg * 8) ^ swz));

            // late ds_write of tile kt+1 (between the two PV halves)
            if (h == 0 && pfn) {
                short* Kn = (short*)Kl[cur ^ 1];
                short* Vn = (short*)Vl[cur ^ 1];
                *(short8*)(Kn + koff0) = kn0;
                *(short8*)(Kn + koff1) = kn1;
                *(short8*)(Vn + voff0) = vn0;
                *(short8*)(Vn + voff1) = vn1;
            }

            // ctx^T += V^T P^T : lane holds q=lm, d = nf*16+lg*4+i
            #pragma unroll
            for (int nf = 0; nf < 4; ++nf) {
                const int rr = nf * 16 + lm;
                #pragma unroll
                for (int ks = 0; ks < 2; ++ks) {
                    const short8 vf = *(const short8*)(Vc + h * 4096 + rr * 64 + ((ks * 4 + lg) ^ swc) * 8);
                    o_acc[nf] = __builtin_amdgcn_mfma_f32_16x16x32_bf16(vf, pf[ks], o_acc[nf], 0, 0, 0);
                }
            }
        }
        cur ^= 1;
    }

    // epilogue: ctx[b][q][h*64 + d] bf16, 8B vector writes
    const float inv = 1.f / l_run;
    const int b = bh >> 4, h = bh & 15;
    short* outp = Ctx + ((size_t)b * 2048 + qrow) * 1024 + h * 64 + lg * 4;
    #pragma unroll
    for (int nf = 0; nf < 4; ++nf) {
        uint2 pk;
        pk.x = pk_bf16(o_acc[nf][0] * inv, o_acc[nf][1] * inv);
        pk.y = pk_bf16(o_acc[nf][2] * inv, o_acc[nf][3] * inv);
        *(uint2*)(outp + nf * 16) = pk;
    }
}

// ---------------------------------------------------------------------------
extern "C" void kernel_launch(void* const* d_in, const int* in_sizes, int n_in,
                              void* d_out, int out_size, void* d_ws, size_t ws_size,
                              hipStream_t stream)
{
    const float* query  = (const float*)d_in[0];
    const float* key_in = (const float*)d_in[1];
    const float* value  = (const float*)d_in[2];
    const float* Wq = (const float*)d_in[3];
    const float* bq = (const float*)d_in[4];
    const float* Wk = (const float*)d_in[5];
    const float* bk = (const float*)d_in[6];
    const float* Wv = (const float*)d_in[7];
    const float* bv = (const float*)d_in[8];
    const float* Wo = (const float*)d_in[9];
    const float* bo = (const float*)d_in[10];
    float* out = (float*)d_out;

    char* ws = (char*)d_ws;
    short* Wt  = (short*)(ws);               // 4 x 2MB transposed bf16 weights
    short* Ctx = (short*)(ws + (8  << 20));  // [B,S,D] 8MB bf16 attn output
    short* Qh  = (short*)(ws + (32 << 20));  // [B,H,S,64] 8MB (scaled 0.125*log2e)
    short* Kh  = (short*)(ws + (40 << 20));  // [B,H,S,64] 8MB
    short* Vt  = (short*)(ws + (48 << 20));  // [B,H,64,S] 8MB

    const float qscale = 0.125f * 1.44269504088896f;  // 1/sqrt(64) * log2(e)

    hipLaunchKernelGGL(prep, dim3(4096), dim3(256), 0, stream,
                       Wq, Wk, Wv, Wo, Wt);
    hipLaunchKernelGGL(gemmqkv, dim3(8, 32, 3), dim3(256), 0, stream,
                       query, key_in, value, Wt, bq, bk, bv, Qh, Kh, Vt, qscale);
    hipLaunchKernelGGL(attn_k, dim3(16, 32), dim3(512), 0, stream,
                       Qh, Kh, Vt, Ctx);
    hipLaunchKernelGGL(gemmo, dim3(8, 64), dim3(256), 0, stream,
                       Ctx, Wt + (3 << 20), bo, out);
}

// Round 18
// 137.972 us; speedup vs baseline: 1.0087x; 1.0087x over previous
//
#include <hip/hip_runtime.h>
#include <hip/hip_bf16.h>

// Problem constants: B=2, S=2048, D=1024, H=16, HD=64, M = B*S = 4096

typedef __attribute__((ext_vector_type(8))) short short8;    // 8 bf16 = 4 VGPR
typedef __attribute__((ext_vector_type(4))) short short4v;   // 4 bf16
typedef __attribute__((ext_vector_type(4))) float f32x4;     // 16x16 C/D frag

static __device__ __forceinline__ short f2bf(float f) {
    union { float f; unsigned u; } c; c.f = f;
    unsigned r = c.u + 0x7fff + ((c.u >> 16) & 1);   // RNE
    return (short)(r >> 16);
}

// packed f32x2 -> bf16x2 (v_cvt_pk_bf16_f32)
static __device__ __forceinline__ unsigned pk_bf16(float a, float b) {
    union { __hip_bfloat162 h; unsigned u; } c;
    c.h = __float22bfloat162_rn(make_float2(a, b));
    return c.u;
}

// async global -> LDS, 16B per lane (global_load_lds_dwordx4).
typedef const void __attribute__((address_space(1)))* gas_ptr;
typedef void __attribute__((address_space(3)))* las_ptr;
static __device__ __forceinline__ void gload16(const void* g, void* l) {
    __builtin_amdgcn_global_load_lds((gas_ptr)g, (las_ptr)l, 16, 0, 0);
}

// ---------------------------------------------------------------------------
// prep: merged f32->bf16 input conversion (3 x 4M elems) + weight transpose
// (4 x W[K][N] f32 -> Wt[N][K] bf16). One dispatch, 10240 blocks.
// (r17's fused-A experiment reverted: net-neutral — prep saved ~11 µs but
//  fused gemmqkv cost ~12 (2x A HBM bytes + in-loop cvt). Separate pass
//  runs at HBM ceiling (~96MB/15µs) and keeps gemmqkv at 920 TF.)
// ---------------------------------------------------------------------------
__global__ __launch_bounds__(256) void prep(
    const float* __restrict__ X0, const float* __restrict__ X1,
    const float* __restrict__ X2, short* __restrict__ Abf,
    const float* __restrict__ W0, const float* __restrict__ W1,
    const float* __restrict__ W2, const float* __restrict__ W3,
    short* __restrict__ Wt)
{
    __shared__ float tile[32][33];
    const int bid = blockIdx.x;
    if (bid < 6144) {           // --- tobf16: 2048 blocks per input ---
        const int zz = bid >> 11, xb = bid & 2047;
        const float* X = zz == 0 ? X0 : zz == 1 ? X1 : X2;
        short* o = Abf + ((size_t)zz << 22);
        const int i = (xb * 256 + threadIdx.x) * 8;
        const float4 a = *(const float4*)(X + i);
        const float4 b = *(const float4*)(X + i + 4);
        uint4 r;
        r.x = pk_bf16(a.x, a.y); r.y = pk_bf16(a.z, a.w);
        r.z = pk_bf16(b.x, b.y); r.w = pk_bf16(b.z, b.w);
        *(uint4*)(o + i) = r;
    } else {                    // --- wtrans: 1024 blocks per weight ---
        const int wid = bid - 6144;
        const int z = wid >> 10;
        const float* W = z == 0 ? W0 : z == 1 ? W1 : z == 2 ? W2 : W3;
        short* O = Wt + ((size_t)z << 20);
        const int k0 = (wid & 31) * 32, n0 = ((wid >> 5) & 31) * 32;
        const int tx = threadIdx.x & 31, ty = threadIdx.x >> 5;  // (32,8)
        #pragma unroll
        for (int j = 0; j < 32; j += 8)
            tile[ty + j][tx] = W[(k0 + ty + j) * 1024 + n0 + tx];
        __syncthreads();
        #pragma unroll
        for (int j = 0; j < 32; j += 8)
            O[(n0 + ty + j) * 1024 + k0 + tx] = f2bf(tile[tx][ty + j]);
    }
}

// ---------------------------------------------------------------------------
// Merged Q/K/V projection GEMM — m97 128x128 structure (r16 config, best):
// BM=BN=128, BK=32, 4 waves x (64x64 quadrant, acc[4][4] of 16x16x32).
// Both operands bf16 staged via global_load_lds dwordx4 (4 chunks/thread),
// double-buffered, 1 barrier/K-step. Grid (8,32,3) = 768 blocks = 3/CU;
// T1 bijective XCD swizzle (768%8==0, 96-block chunks).
// ---------------------------------------------------------------------------
__global__ __launch_bounds__(256, 3) void gemmqkv(
    const short* __restrict__ Abase, const short* __restrict__ Wt,
    const float* __restrict__ bq, const float* __restrict__ bk,
    const float* __restrict__ bv, short* __restrict__ Qh,
    short* __restrict__ Kh, short* __restrict__ Vt, float qscale)
{
    __shared__ short Al[2][4096];   // [128 m][32 k]
    __shared__ short Bl[2][4096];   // [128 n][32 k]
    const int flat = blockIdx.z * 256 + blockIdx.y * 8 + blockIdx.x;
    const int remap = (flat & 7) * 96 + (flat >> 3);   // 768 % 8 == 0: bijective
    const int z = remap >> 8;
    const int rem = remap & 255;
    const int m0 = (rem >> 3) * 128, n0 = (rem & 7) * 128;

    const short* Aa = Abase + ((size_t)z << 22);
    const short* Ba = Wt + ((size_t)z << 20);
    const float* bias = z == 0 ? bq : z == 1 ? bk : bv;
    short* O = z == 0 ? Qh : z == 1 ? Kh : Vt;
    const float scale = z == 0 ? qscale : 1.0f;

    const int t = threadIdx.x;
    const int lane = t & 63, w = t >> 6;
    const int lm = lane & 15, lg = lane >> 4;
    const int wr = w >> 1, wc = w & 1;

    #define STAGEQ(buf, k0) do {                                              \
        _Pragma("unroll")                                                     \
        for (int j = 0; j < 2; ++j) {                                         \
            const int c = j * 256 + t;                                        \
            gload16(Aa + (size_t)(m0 + (c >> 2)) * 1024 + (k0) + (c & 3) * 8, \
                    &Al[buf][j * 2048 + w * 512]);                            \
            gload16(Ba + (size_t)(n0 + (c >> 2)) * 1024 + (k0) + (c & 3) * 8, \
                    &Bl[buf][j * 2048 + w * 512]);                            \
        }                                                                     \
    } while (0)

    f32x4 acc[4][4] = {};
    STAGEQ(0, 0);
    __syncthreads();

    int buf = 0;
    for (int kk = 0; kk < 32; ++kk) {
        if (kk < 31) STAGEQ(buf ^ 1, (kk + 1) * 32);
        const short* Ab = Al[buf];
        const short* Bb = Bl[buf];
        short8 af[4], bfr[4];
        #pragma unroll
        for (int mf = 0; mf < 4; ++mf)
            af[mf] = *(const short8*)(Ab + (wr * 64 + mf * 16 + lm) * 32 + lg * 8);
        #pragma unroll
        for (int nf = 0; nf < 4; ++nf)
            bfr[nf] = *(const short8*)(Bb + (wc * 64 + nf * 16 + lm) * 32 + lg * 8);
        #pragma unroll
        for (int mf = 0; mf < 4; ++mf)
            #pragma unroll
            for (int nf = 0; nf < 4; ++nf)
                acc[mf][nf] = __builtin_amdgcn_mfma_f32_16x16x32_bf16(
                    af[mf], bfr[nf], acc[mf][nf], 0, 0, 0);
        __syncthreads();
        buf ^= 1;
    }
    #undef STAGEQ

    // epilogue — D frag: col = lm (n), rows = lg*4 + i (m)
    #pragma unroll
    for (int mf = 0; mf < 4; ++mf) {
        const int mb = m0 + wr * 64 + mf * 16 + lg * 4;
        #pragma unroll
        for (int nf = 0; nf < 4; ++nf) {
            const int n = n0 + wc * 64 + nf * 16 + lm;
            const float bs = bias[n];
            if (z == 2) {   // V^T [B,H,64,S]: 4 consecutive s per lane
                short4v sv;
                #pragma unroll
                for (int i = 0; i < 4; ++i)
                    sv[i] = f2bf(acc[mf][nf][i] + bs);
                const int addr = (((mb >> 11) * 16 + (n >> 6)) * 64 + (n & 63)) * 2048 + (mb & 2047);
                *(short4v*)&O[addr] = sv;
            } else {        // head-split [B,H,S,64]
                #pragma unroll
                for (int i = 0; i < 4; ++i) {
                    const int m = mb + i;
                    const int addr = (((m >> 11) * 16 + (n >> 6)) * 2048 + (m & 2047)) * 64 + (n & 63);
                    O[addr] = f2bf(scale * (acc[mf][nf][i] + bs));
                }
            }
        }
    }
}

// ---------------------------------------------------------------------------
// GEMM core (BM=64, BN=128, BK=32), 4 waves — kept for gemmo (512 blocks =
// 2/CU; a 128^2 gemmo would be 256 blocks = 1/CU, the r4 starvation regime).
// ---------------------------------------------------------------------------
#define STAGE(buf, k0) do {                                                   \
    gload16(Aa + (size_t)(gm0 + (t >> 2)) * 1024 + (k0) + (t & 3) * 8,        \
            &Al[buf][w * 512]);                                               \
    _Pragma("unroll")                                                         \
    for (int j = 0; j < 2; ++j) {                                             \
        const int c = j * 256 + t;                                            \
        gload16(Ba + (size_t)(gn0 + (c >> 2)) * 1024 + (k0) + (c & 3) * 8,    \
                &Bl[buf][j * 2048 + w * 512]);                                \
    }                                                                         \
} while (0)

#define GEMM_CORE(Aa_, Ba_, m0v, n0v)                                         \
    __shared__ short Al[2][2048];   /* [64 m][32 k] */                        \
    __shared__ short Bl[2][4096];   /* [128 n][32 k] */                       \
    const int t = threadIdx.x;                                                \
    const int gm0 = (m0v), gn0 = (n0v);                                       \
    const int lane = t & 63, w = t >> 6;                                      \
    const int lm = lane & 15, lg = lane >> 4;                                 \
    const int wr = w >> 1, wc = w & 1;                                        \
    f32x4 acc[2][4] = {};                                                     \
    STAGE(0, 0);                                                              \
    __syncthreads();                                                          \
    int buf = 0;                                                              \
    for (int kk = 0; kk < 32; ++kk) {                                         \
        if (kk < 31) STAGE(buf ^ 1, (kk + 1) * 32);                           \
        const short* Ab = Al[buf];                                            \
        const short* Bb = Bl[buf];                                            \
        short8 af[2], bfr[4];                                                 \
        _Pragma("unroll")                                                     \
        for (int mf = 0; mf < 2; ++mf)                                        \
            af[mf] = *(const short8*)(Ab + (wr * 32 + mf * 16 + lm) * 32 + lg * 8); \
        _Pragma("unroll")                                                     \
        for (int nf = 0; nf < 4; ++nf)                                        \
            bfr[nf] = *(const short8*)(Bb + (wc * 64 + nf * 16 + lm) * 32 + lg * 8); \
        _Pragma("unroll")                                                     \
        for (int mf = 0; mf < 2; ++mf)                                        \
            _Pragma("unroll")                                                 \
            for (int nf = 0; nf < 4; ++nf)                                    \
                acc[mf][nf] = __builtin_amdgcn_mfma_f32_16x16x32_bf16(        \
                    af[mf], bfr[nf], acc[mf][nf], 0, 0, 0);                   \
        __syncthreads();                                                      \
        buf ^= 1;                                                             \
    }

// ---------------------------------------------------------------------------
// Final projection: out = Ctx @ Wo^T + bo, f32 flat. 512 blocks, XCD swizzle.
// ---------------------------------------------------------------------------
__global__ __launch_bounds__(256) void gemmo(
    const short* __restrict__ Aa, const short* __restrict__ Ba,
    const float* __restrict__ bias, float* __restrict__ Out)
{
    const int flat = blockIdx.y * 8 + blockIdx.x;
    const int remap = (flat & 7) * 64 + (flat >> 3);    // 512 % 8 == 0: bijective
    const int m0 = (remap >> 3) * 64, n0 = (remap & 7) * 128;

    GEMM_CORE(Aa, Ba, m0, n0)

    #pragma unroll
    for (int mf = 0; mf < 2; ++mf) {
        const int mb = m0 + wr * 32 + mf * 16 + lg * 4;
        #pragma unroll
        for (int nf = 0; nf < 4; ++nf) {
            const int n = n0 + wc * 64 + nf * 16 + lm;
            const float bs = bias[n];
            #pragma unroll
            for (int i = 0; i < 4; ++i)
                Out[(mb + i) * 1024 + n] = acc[mf][nf][i] + bs;
        }
    }
}
#undef STAGE
#undef GEMM_CORE

// ---------------------------------------------------------------------------
// Flash attention v13 = v12 (best, ~74 µs) + T5 setprio around the MFMA
// clusters. Rationale: m191 measured +4-7% on attn when waves have phase
// diversity — this 8-wave structure has 16 waves/CU diverging through
// softmax/PV between barriers (unlike the r3 4-wave kernel where setprio
// was confounded). GEMMs stay setprio-free (m190: null/negative).
// Unchanged: 8 waves x 16 q-rows, KVBLK=128/barrier, V tile as two [64][64]
// halves, XOR chunk swizzle, double-buffer + T14, 1 barrier/tile, swapped
// QK^T/PV, exp2 softmax, defer-max, tree reductions, XCD-chunked remap.
// ---------------------------------------------------------------------------
__global__ __launch_bounds__(512, 4) void attn_k(
    const short* __restrict__ Q, const short* __restrict__ K,
    const short* __restrict__ V, short* __restrict__ Ctx)
{
    __shared__ short Kl[2][128][64];
    __shared__ short Vl[2][2][64][64];   // [buf][key-half][d-row][key-chunk]
    __shared__ short Pl[8][16][64];
    const int t = threadIdx.x;
    const int flat = blockIdx.y * 16 + blockIdx.x;
    const int remap = (flat & 7) * 64 + (flat >> 3);   // 512 % 8 == 0: bijective
    const int qt = remap & 15, bh = remap >> 4;        // XCD c -> bh in [4c,4c+4)
    const int lane = t & 63, w = t >> 6;   // 8 waves
    const int lm = lane & 15, lg = lane >> 4;
    const int swz = (lm & 7) << 3;          // P-buffer swizzle (shorts)
    const int swc = lm & 7;                 // K/V read chunk swizzle

    const int qrow = qt * 128 + w * 16 + lm;
    short8 qf[2];
    #pragma unroll
    for (int ks = 0; ks < 2; ++ks)
        qf[ks] = *(const short8*)(Q + ((size_t)bh * 2048 + qrow) * 64 + ks * 32 + lg * 8);

    float m_run = -3e38f, l_run = 0.f;
    f32x4 o_acc[4] = {};

    const int rk = t >> 2, ck = t & 3;
    const int rv = t >> 3, cv = t & 7;
    const short* Kg = K + ((size_t)bh * 2048 + rk) * 64 + ck * 16;
    const short* Vg = V + ((size_t)bh * 64 + rv) * 2048 + cv * 16;
    const int koff0 = rk * 64 + ((ck * 2) ^ (rk & 7)) * 8;
    const int koff1 = rk * 64 + ((ck * 2 + 1) ^ (rk & 7)) * 8;
    const int vhalf = (cv >> 2) * 4096;
    const int voff0 = vhalf + rv * 64 + (((cv * 2) & 7) ^ (rv & 7)) * 8;
    const int voff1 = vhalf + rv * 64 + (((cv * 2 + 1) & 7) ^ (rv & 7)) * 8;

    {   // prologue: stage tile 0 into buffer 0
        short8 a = *(const short8*)(Kg);
        short8 b = *(const short8*)(Kg + 8);
        short8 c = *(const short8*)(Vg);
        short8 d = *(const short8*)(Vg + 8);
        *(short8*)((short*)Kl[0] + koff0) = a;
        *(short8*)((short*)Kl[0] + koff1) = b;
        *(short8*)((short*)Vl[0] + voff0) = c;
        *(short8*)((short*)Vl[0] + voff1) = d;
    }

    short* prow = &Pl[w][lm][0];
    int cur = 0;

    for (int kt = 0; kt < 16; ++kt) {
        __syncthreads();   // stage[cur] visible; [cur^1] free for writing

        // early-issue global loads for tile kt+1 (T14)
        short8 kn0, kn1, vn0, vn1;
        const bool pfn = (kt < 15);
        if (pfn) {
            const short* Kgn = Kg + (size_t)(kt + 1) * 8192;   // 128 rows * 64
            const short* Vgn = Vg + (kt + 1) * 128;
            kn0 = *(const short8*)(Kgn);
            kn1 = *(const short8*)(Kgn + 8);
            vn0 = *(const short8*)(Vgn);
            vn1 = *(const short8*)(Vgn + 8);
        }

        const short* Kc = (const short*)Kl[cur];
        const short* Vc = (const short*)Vl[cur];

        // ---- S^T = K Q^T, BOTH halves: lane holds q=lm, 32 key-vals ----
        f32x4 sa[2][4] = {};
        __builtin_amdgcn_s_setprio(1);
        #pragma unroll
        for (int h = 0; h < 2; ++h)
            #pragma unroll
            for (int nf = 0; nf < 4; ++nf) {
                const int rr = h * 64 + nf * 16 + lm;
                #pragma unroll
                for (int ks = 0; ks < 2; ++ks) {
                    const short8 kf = *(const short8*)(Kc + rr * 64 + ((ks * 4 + lg) ^ swc) * 8);
                    sa[h][nf] = __builtin_amdgcn_mfma_f32_16x16x32_bf16(kf, qf[ks], sa[h][nf], 0, 0, 0);
                }
            }
        __builtin_amdgcn_s_setprio(0);

        // ---- max reduce: pairwise tree (fmaxf nests fuse to v_max3) ----
        float mx[8];
        #pragma unroll
        for (int h = 0; h < 2; ++h)
            #pragma unroll
            for (int nf = 0; nf < 4; ++nf) {
                const f32x4 v = sa[h][nf];
                mx[h * 4 + nf] = fmaxf(fmaxf(v[0], v[1]), fmaxf(v[2], v[3]));
            }
        float mt = fmaxf(fmaxf(fmaxf(mx[0], mx[1]), fmaxf(mx[2], mx[3])),
                         fmaxf(fmaxf(mx[4], mx[5]), fmaxf(mx[6], mx[7])));
        mt = fmaxf(mt, __shfl_xor(mt, 16));
        mt = fmaxf(mt, __shfl_xor(mt, 32));
        if (__any(mt > m_run + 8.0f)) {     // defer-max (T13)
            const float mn = fmaxf(m_run, mt);
            const float alpha = exp2f(m_run - mn);
            l_run *= alpha;
            #pragma unroll
            for (int nf = 0; nf < 4; ++nf)
                #pragma unroll
                for (int i = 0; i < 4; ++i)
                    o_acc[nf][i] *= alpha;
            m_run = mn;
        }
        // exp2 + tree-structured sum (8 frag-partials -> 3-level tree)
        float ps[8];
        #pragma unroll
        for (int h = 0; h < 2; ++h)
            #pragma unroll
            for (int nf = 0; nf < 4; ++nf) {
                f32x4 v = sa[h][nf];
                #pragma unroll
                for (int i = 0; i < 4; ++i) v[i] = exp2f(v[i] - m_run);
                sa[h][nf] = v;
                ps[h * 4 + nf] = (v[0] + v[1]) + (v[2] + v[3]);
            }
        float rs = ((ps[0] + ps[1]) + (ps[2] + ps[3])) +
                   ((ps[4] + ps[5]) + (ps[6] + ps[7]));
        rs += __shfl_xor(rs, 16);
        rs += __shfl_xor(rs, 32);
        l_run += rs;

        // ---- per key-half: P-pack -> pf -> PV (P buffer reused) ----
        #pragma unroll
        for (int h = 0; h < 2; ++h) {
            #pragma unroll
            for (int nf = 0; nf < 4; ++nf) {
                uint2 pv;
                pv.x = pk_bf16(sa[h][nf][0], sa[h][nf][1]);
                pv.y = pk_bf16(sa[h][nf][2], sa[h][nf][3]);
                *(uint2*)(prow + ((nf * 16 + lg * 4) ^ swz)) = pv;
            }
            short8 pf[2];
            #pragma unroll
            for (int ks = 0; ks < 2; ++ks)
                pf[ks] = *(const short8*)(prow + ((ks * 32 + lg * 8) ^ swz));

            // late ds_write of tile kt+1 (between the two PV halves)
            if (h == 0 && pfn) {
                short* Kn = (short*)Kl[cur ^ 1];
                short* Vn = (short*)Vl[cur ^ 1];
                *(short8*)(Kn + koff0) = kn0;
                *(short8*)(Kn + koff1) = kn1;
                *(short8*)(Vn + voff0) = vn0;
                *(short8*)(Vn + voff1) = vn1;
            }

            // ctx^T += V^T P^T : lane holds q=lm, d = nf*16+lg*4+i
            __builtin_amdgcn_s_setprio(1);
            #pragma unroll
            for (int nf = 0; nf < 4; ++nf) {
                const int rr = nf * 16 + lm;
                #pragma unroll
                for (int ks = 0; ks < 2; ++ks) {
                    const short8 vf = *(const short8*)(Vc + h * 4096 + rr * 64 + ((ks * 4 + lg) ^ swc) * 8);
                    o_acc[nf] = __builtin_amdgcn_mfma_f32_16x16x32_bf16(vf, pf[ks], o_acc[nf], 0, 0, 0);
                }
            }
            __builtin_amdgcn_s_setprio(0);
        }
        cur ^= 1;
    }

    // epilogue: ctx[b][q][h*64 + d] bf16, 8B vector writes
    const float inv = 1.f / l_run;
    const int b = bh >> 4, h = bh & 15;
    short* outp = Ctx + ((size_t)b * 2048 + qrow) * 1024 + h * 64 + lg * 4;
    #pragma unroll
    for (int nf = 0; nf < 4; ++nf) {
        uint2 pk;
        pk.x = pk_bf16(o_acc[nf][0] * inv, o_acc[nf][1] * inv);
        pk.y = pk_bf16(o_acc[nf][2] * inv, o_acc[nf][3] * inv);
        *(uint2*)(outp + nf * 16) = pk;
    }
}

// ---------------------------------------------------------------------------
extern "C" void kernel_launch(void* const* d_in, const int* in_sizes, int n_in,
                              void* d_out, int out_size, void* d_ws, size_t ws_size,
                              hipStream_t stream)
{
    const float* query  = (const float*)d_in[0];
    const float* key_in = (const float*)d_in[1];
    const float* value  = (const float*)d_in[2];
    const float* Wq = (const float*)d_in[3];
    const float* bq = (const float*)d_in[4];
    const float* Wk = (const float*)d_in[5];
    const float* bk = (const float*)d_in[6];
    const float* Wv = (const float*)d_in[7];
    const float* bv = (const float*)d_in[8];
    const float* Wo = (const float*)d_in[9];
    const float* bo = (const float*)d_in[10];
    float* out = (float*)d_out;

    char* ws = (char*)d_ws;
    short* Wt  = (short*)(ws);               // 4 x 2MB transposed bf16 weights
    short* Abf = (short*)(ws + (8  << 20));  // 3 x 8MB bf16 inputs (q,k,v)
    short* Qh  = (short*)(ws + (32 << 20));  // [B,H,S,64] 8MB (scaled 0.125*log2e)
    short* Kh  = (short*)(ws + (40 << 20));  // [B,H,S,64] 8MB
    short* Vt  = (short*)(ws + (48 << 20));  // [B,H,64,S] 8MB
    short* Ctx = Abf;                        // Abf dead after QKV gemm; alias

    const float qscale = 0.125f * 1.44269504088896f;  // 1/sqrt(64) * log2(e)

    hipLaunchKernelGGL(prep, dim3(10240), dim3(256), 0, stream,
                       query, key_in, value, Abf, Wq, Wk, Wv, Wo, Wt);
    hipLaunchKernelGGL(gemmqkv, dim3(8, 32, 3), dim3(256), 0, stream,
                       Abf, Wt, bq, bk, bv, Qh, Kh, Vt, qscale);
    hipLaunchKernelGGL(attn_k, dim3(16, 32), dim3(512), 0, stream,
                       Qh, Kh, Vt, Ctx);
    hipLaunchKernelGGL(gemmo, dim3(8, 64), dim3(256), 0, stream,
                       Ctx, Wt + (3 << 20), bo, out);
}

// Round 19
// 135.352 us; speedup vs baseline: 1.0282x; 1.0194x over previous
//
#include <hip/hip_runtime.h>
#include <hip/hip_bf16.h>

// Problem constants: B=2, S=2048, D=1024, H=16, HD=64, M = B*S = 4096

typedef __attribute__((ext_vector_type(8))) short short8;    // 8 bf16 = 4 VGPR
typedef __attribute__((ext_vector_type(4))) short short4v;   // 4 bf16
typedef __attribute__((ext_vector_type(4))) float f32x4;     // 16x16 C/D frag

static __device__ __forceinline__ short f2bf(float f) {
    union { float f; unsigned u; } c; c.f = f;
    unsigned r = c.u + 0x7fff + ((c.u >> 16) & 1);   // RNE
    return (short)(r >> 16);
}

// packed f32x2 -> bf16x2 (v_cvt_pk_bf16_f32)
static __device__ __forceinline__ unsigned pk_bf16(float a, float b) {
    union { __hip_bfloat162 h; unsigned u; } c;
    c.h = __float22bfloat162_rn(make_float2(a, b));
    return c.u;
}

// async global -> LDS, 16B per lane (global_load_lds_dwordx4).
typedef const void __attribute__((address_space(1)))* gas_ptr;
typedef void __attribute__((address_space(3)))* las_ptr;
static __device__ __forceinline__ void gload16(const void* g, void* l) {
    __builtin_amdgcn_global_load_lds((gas_ptr)g, (las_ptr)l, 16, 0, 0);
}

// ---------------------------------------------------------------------------
// prep: merged f32->bf16 input conversion (3 x 4M elems) + weight transpose
// (4 x W[K][N] f32 -> Wt[N][K] bf16). One dispatch, 10240 blocks. At HBM
// roofline (~96 MB @ ~6.4 TB/s ~= 15 us).
// ---------------------------------------------------------------------------
__global__ __launch_bounds__(256) void prep(
    const float* __restrict__ X0, const float* __restrict__ X1,
    const float* __restrict__ X2, short* __restrict__ Abf,
    const float* __restrict__ W0, const float* __restrict__ W1,
    const float* __restrict__ W2, const float* __restrict__ W3,
    short* __restrict__ Wt)
{
    __shared__ float tile[32][33];
    const int bid = blockIdx.x;
    if (bid < 6144) {           // --- tobf16: 2048 blocks per input ---
        const int zz = bid >> 11, xb = bid & 2047;
        const float* X = zz == 0 ? X0 : zz == 1 ? X1 : X2;
        short* o = Abf + ((size_t)zz << 22);
        const int i = (xb * 256 + threadIdx.x) * 8;
        const float4 a = *(const float4*)(X + i);
        const float4 b = *(const float4*)(X + i + 4);
        uint4 r;
        r.x = pk_bf16(a.x, a.y); r.y = pk_bf16(a.z, a.w);
        r.z = pk_bf16(b.x, b.y); r.w = pk_bf16(b.z, b.w);
        *(uint4*)(o + i) = r;
    } else {                    // --- wtrans: 1024 blocks per weight ---
        const int wid = bid - 6144;
        const int z = wid >> 10;
        const float* W = z == 0 ? W0 : z == 1 ? W1 : z == 2 ? W2 : W3;
        short* O = Wt + ((size_t)z << 20);
        const int k0 = (wid & 31) * 32, n0 = ((wid >> 5) & 31) * 32;
        const int tx = threadIdx.x & 31, ty = threadIdx.x >> 5;  // (32,8)
        #pragma unroll
        for (int j = 0; j < 32; j += 8)
            tile[ty + j][tx] = W[(k0 + ty + j) * 1024 + n0 + tx];
        __syncthreads();
        #pragma unroll
        for (int j = 0; j < 32; j += 8)
            O[(n0 + ty + j) * 1024 + k0 + tx] = f2bf(tile[tx][ty + j]);
    }
}

// ---------------------------------------------------------------------------
// Merged Q/K/V projection GEMM — m97 128x128 structure (r16 config, best):
// BM=BN=128, BK=32, 4 waves x (64x64 quadrant, acc[4][4] of 16x16x32).
// Both operands bf16 staged via global_load_lds dwordx4, double-buffered,
// 1 barrier/K-step. Grid (8,32,3) = 768 blocks = 3/CU; T1 bijective XCD
// swizzle. (No LDS read-swizzle: T2 regime-gate says conflict fixes are
// null at 2-phase — m252.)
// ---------------------------------------------------------------------------
__global__ __launch_bounds__(256, 3) void gemmqkv(
    const short* __restrict__ Abase, const short* __restrict__ Wt,
    const float* __restrict__ bq, const float* __restrict__ bk,
    const float* __restrict__ bv, short* __restrict__ Qh,
    short* __restrict__ Kh, short* __restrict__ Vt, float qscale)
{
    __shared__ short Al[2][4096];   // [128 m][32 k]
    __shared__ short Bl[2][4096];   // [128 n][32 k]
    const int flat = blockIdx.z * 256 + blockIdx.y * 8 + blockIdx.x;
    const int remap = (flat & 7) * 96 + (flat >> 3);   // 768 % 8 == 0: bijective
    const int z = remap >> 8;
    const int rem = remap & 255;
    const int m0 = (rem >> 3) * 128, n0 = (rem & 7) * 128;

    const short* Aa = Abase + ((size_t)z << 22);
    const short* Ba = Wt + ((size_t)z << 20);
    const float* bias = z == 0 ? bq : z == 1 ? bk : bv;
    short* O = z == 0 ? Qh : z == 1 ? Kh : Vt;
    const float scale = z == 0 ? qscale : 1.0f;

    const int t = threadIdx.x;
    const int lane = t & 63, w = t >> 6;
    const int lm = lane & 15, lg = lane >> 4;
    const int wr = w >> 1, wc = w & 1;

    #define STAGEQ(buf, k0) do {                                              \
        _Pragma("unroll")                                                     \
        for (int j = 0; j < 2; ++j) {                                         \
            const int c = j * 256 + t;                                        \
            gload16(Aa + (size_t)(m0 + (c >> 2)) * 1024 + (k0) + (c & 3) * 8, \
                    &Al[buf][j * 2048 + w * 512]);                            \
            gload16(Ba + (size_t)(n0 + (c >> 2)) * 1024 + (k0) + (c & 3) * 8, \
                    &Bl[buf][j * 2048 + w * 512]);                            \
        }                                                                     \
    } while (0)

    f32x4 acc[4][4] = {};
    STAGEQ(0, 0);
    __syncthreads();

    int buf = 0;
    for (int kk = 0; kk < 32; ++kk) {
        if (kk < 31) STAGEQ(buf ^ 1, (kk + 1) * 32);
        const short* Ab = Al[buf];
        const short* Bb = Bl[buf];
        short8 af[4], bfr[4];
        #pragma unroll
        for (int mf = 0; mf < 4; ++mf)
            af[mf] = *(const short8*)(Ab + (wr * 64 + mf * 16 + lm) * 32 + lg * 8);
        #pragma unroll
        for (int nf = 0; nf < 4; ++nf)
            bfr[nf] = *(const short8*)(Bb + (wc * 64 + nf * 16 + lm) * 32 + lg * 8);
        #pragma unroll
        for (int mf = 0; mf < 4; ++mf)
            #pragma unroll
            for (int nf = 0; nf < 4; ++nf)
                acc[mf][nf] = __builtin_amdgcn_mfma_f32_16x16x32_bf16(
                    af[mf], bfr[nf], acc[mf][nf], 0, 0, 0);
        __syncthreads();
        buf ^= 1;
    }
    #undef STAGEQ

    // epilogue — D frag: col = lm (n), rows = lg*4 + i (m)
    #pragma unroll
    for (int mf = 0; mf < 4; ++mf) {
        const int mb = m0 + wr * 64 + mf * 16 + lg * 4;
        #pragma unroll
        for (int nf = 0; nf < 4; ++nf) {
            const int n = n0 + wc * 64 + nf * 16 + lm;
            const float bs = bias[n];
            if (z == 2) {   // V^T [B,H,64,S]: 4 consecutive s per lane
                short4v sv;
                #pragma unroll
                for (int i = 0; i < 4; ++i)
                    sv[i] = f2bf(acc[mf][nf][i] + bs);
                const int addr = (((mb >> 11) * 16 + (n >> 6)) * 64 + (n & 63)) * 2048 + (mb & 2047);
                *(short4v*)&O[addr] = sv;
            } else {        // head-split [B,H,S,64]
                #pragma unroll
                for (int i = 0; i < 4; ++i) {
                    const int m = mb + i;
                    const int addr = (((m >> 11) * 16 + (n >> 6)) * 2048 + (m & 2047)) * 64 + (n & 63);
                    O[addr] = f2bf(scale * (acc[mf][nf][i] + bs));
                }
            }
        }
    }
}

// ---------------------------------------------------------------------------
// Final projection v2: out = Ctx @ Wo^T + bo, f32 flat. BM=64, BN=128,
// BK=64 (barriers 32 -> 16, 16 MFMA/wave/barrier — attacks the 2-phase
// barrier-drain cost, m233). [row][64-short] rows are 128B = 16-way read
// conflict, fixed per rule 21c: gload16 LINEAR dest + PRE-SWIZZLED global
// source (kc ^= row&7) + same XOR on the frag read (attn's proven pattern).
// LDS 48KB; grid (8,64) = 512 blocks = 2/CU (grid-capped; no occupancy
// loss from the bigger tiles). T1 XCD swizzle kept.
// ---------------------------------------------------------------------------
__global__ __launch_bounds__(256) void gemmo(
    const short* __restrict__ Aa, const short* __restrict__ Ba,
    const float* __restrict__ bias, float* __restrict__ Out)
{
    __shared__ short Al[2][4096];   // [64 m][64 k], source-swizzled
    __shared__ short Bl[2][8192];   // [128 n][64 k], source-swizzled
    const int flat = blockIdx.y * 8 + blockIdx.x;
    const int remap = (flat & 7) * 64 + (flat >> 3);    // 512 % 8 == 0: bijective
    const int m0 = (remap >> 3) * 64, n0 = (remap & 7) * 128;

    const int t = threadIdx.x;
    const int lane = t & 63, w = t >> 6;
    const int lm = lane & 15, lg = lane >> 4;
    const int wr = w >> 1, wc = w & 1;
    const int sw = lm & 7;          // frag-read chunk swizzle (row&7 == lm&7)

    // staging: A 512 chunks (2/thread), B 1024 chunks (4/thread); LDS dest
    // linear c*8 (wave-contiguous); global source k-chunk = (c&7) ^ (row&7).
    #define STAGEO(buf, k0) do {                                              \
        _Pragma("unroll")                                                     \
        for (int j = 0; j < 2; ++j) {                                         \
            const int c = j * 256 + t;                                        \
            gload16(Aa + (size_t)(m0 + (c >> 3)) * 1024 + (k0)                \
                        + (((c & 7) ^ ((c >> 3) & 7)) * 8),                   \
                    &Al[buf][j * 2048 + t * 8]);                              \
        }                                                                     \
        _Pragma("unroll")                                                     \
        for (int j = 0; j < 4; ++j) {                                         \
            const int c = j * 256 + t;                                        \
            gload16(Ba + (size_t)(n0 + (c >> 3)) * 1024 + (k0)                \
                        + (((c & 7) ^ ((c >> 3) & 7)) * 8),                   \
                    &Bl[buf][j * 2048 + t * 8]);                              \
        }                                                                     \
    } while (0)

    f32x4 acc[2][4] = {};
    STAGEO(0, 0);
    __syncthreads();

    int buf = 0;
    for (int kk = 0; kk < 16; ++kk) {
        if (kk < 15) STAGEO(buf ^ 1, (kk + 1) * 64);
        const short* Ab = Al[buf];
        const short* Bb = Bl[buf];
        #pragma unroll
        for (int ks = 0; ks < 2; ++ks) {
            short8 af[2], bfr[4];
            #pragma unroll
            for (int mf = 0; mf < 2; ++mf)
                af[mf] = *(const short8*)(Ab + (wr * 32 + mf * 16 + lm) * 64
                                             + (((ks * 4 + lg) ^ sw) * 8));
            #pragma unroll
            for (int nf = 0; nf < 4; ++nf)
                bfr[nf] = *(const short8*)(Bb + (wc * 64 + nf * 16 + lm) * 64
                                              + (((ks * 4 + lg) ^ sw) * 8));
            #pragma unroll
            for (int mf = 0; mf < 2; ++mf)
                #pragma unroll
                for (int nf = 0; nf < 4; ++nf)
                    acc[mf][nf] = __builtin_amdgcn_mfma_f32_16x16x32_bf16(
                        af[mf], bfr[nf], acc[mf][nf], 0, 0, 0);
        }
        __syncthreads();
        buf ^= 1;
    }
    #undef STAGEO

    #pragma unroll
    for (int mf = 0; mf < 2; ++mf) {
        const int mb = m0 + wr * 32 + mf * 16 + lg * 4;
        #pragma unroll
        for (int nf = 0; nf < 4; ++nf) {
            const int n = n0 + wc * 64 + nf * 16 + lm;
            const float bs = bias[n];
            #pragma unroll
            for (int i = 0; i < 4; ++i)
                Out[(mb + i) * 1024 + n] = acc[mf][nf][i] + bs;
        }
    }
}

// ---------------------------------------------------------------------------
// Flash attention v14 = v13 + lazy max-reduce: the T13 gate now tests the
// PER-LANE max (__any supplies the cross-lane vote); the 2-shuffle full
// reduce runs only inside the rarely-taken rescale branch. Common path has
// ZERO max shuffles; exp values bounded by 2^8 (HK THR=8 semantics, safe in
// f32 accum / bf16 P). m_run stays wave-uniform (updated only from the
// wave-reduced max). Everything else identical to the banked best.
// ---------------------------------------------------------------------------
__global__ __launch_bounds__(512, 4) void attn_k(
    const short* __restrict__ Q, const short* __restrict__ K,
    const short* __restrict__ V, short* __restrict__ Ctx)
{
    __shared__ short Kl[2][128][64];
    __shared__ short Vl[2][2][64][64];   // [buf][key-half][d-row][key-chunk]
    __shared__ short Pl[8][16][64];
    const int t = threadIdx.x;
    const int flat = blockIdx.y * 16 + blockIdx.x;
    const int remap = (flat & 7) * 64 + (flat >> 3);   // 512 % 8 == 0: bijective
    const int qt = remap & 15, bh = remap >> 4;        // XCD c -> bh in [4c,4c+4)
    const int lane = t & 63, w = t >> 6;   // 8 waves
    const int lm = lane & 15, lg = lane >> 4;
    const int swz = (lm & 7) << 3;          // P-buffer swizzle (shorts)
    const int swc = lm & 7;                 // K/V read chunk swizzle

    const int qrow = qt * 128 + w * 16 + lm;
    short8 qf[2];
    #pragma unroll
    for (int ks = 0; ks < 2; ++ks)
        qf[ks] = *(const short8*)(Q + ((size_t)bh * 2048 + qrow) * 64 + ks * 32 + lg * 8);

    float m_run = -3e38f, l_run = 0.f;
    f32x4 o_acc[4] = {};

    const int rk = t >> 2, ck = t & 3;
    const int rv = t >> 3, cv = t & 7;
    const short* Kg = K + ((size_t)bh * 2048 + rk) * 64 + ck * 16;
    const short* Vg = V + ((size_t)bh * 64 + rv) * 2048 + cv * 16;
    const int koff0 = rk * 64 + ((ck * 2) ^ (rk & 7)) * 8;
    const int koff1 = rk * 64 + ((ck * 2 + 1) ^ (rk & 7)) * 8;
    const int vhalf = (cv >> 2) * 4096;
    const int voff0 = vhalf + rv * 64 + (((cv * 2) & 7) ^ (rv & 7)) * 8;
    const int voff1 = vhalf + rv * 64 + (((cv * 2 + 1) & 7) ^ (rv & 7)) * 8;

    {   // prologue: stage tile 0 into buffer 0
        short8 a = *(const short8*)(Kg);
        short8 b = *(const short8*)(Kg + 8);
        short8 c = *(const short8*)(Vg);
        short8 d = *(const short8*)(Vg + 8);
        *(short8*)((short*)Kl[0] + koff0) = a;
        *(short8*)((short*)Kl[0] + koff1) = b;
        *(short8*)((short*)Vl[0] + voff0) = c;
        *(short8*)((short*)Vl[0] + voff1) = d;
    }

    short* prow = &Pl[w][lm][0];
    int cur = 0;

    for (int kt = 0; kt < 16; ++kt) {
        __syncthreads();   // stage[cur] visible; [cur^1] free for writing

        // early-issue global loads for tile kt+1 (T14)
        short8 kn0, kn1, vn0, vn1;
        const bool pfn = (kt < 15);
        if (pfn) {
            const short* Kgn = Kg + (size_t)(kt + 1) * 8192;   // 128 rows * 64
            const short* Vgn = Vg + (kt + 1) * 128;
            kn0 = *(const short8*)(Kgn);
            kn1 = *(const short8*)(Kgn + 8);
            vn0 = *(const short8*)(Vgn);
            vn1 = *(const short8*)(Vgn + 8);
        }

        const short* Kc = (const short*)Kl[cur];
        const short* Vc = (const short*)Vl[cur];

        // ---- S^T = K Q^T, BOTH halves: lane holds q=lm, 32 key-vals ----
        f32x4 sa[2][4] = {};
        __builtin_amdgcn_s_setprio(1);
        #pragma unroll
        for (int h = 0; h < 2; ++h)
            #pragma unroll
            for (int nf = 0; nf < 4; ++nf) {
                const int rr = h * 64 + nf * 16 + lm;
                #pragma unroll
                for (int ks = 0; ks < 2; ++ks) {
                    const short8 kf = *(const short8*)(Kc + rr * 64 + ((ks * 4 + lg) ^ swc) * 8);
                    sa[h][nf] = __builtin_amdgcn_mfma_f32_16x16x32_bf16(kf, qf[ks], sa[h][nf], 0, 0, 0);
                }
            }
        __builtin_amdgcn_s_setprio(0);

        // ---- per-lane max (tree, no shuffles in the common path) ----
        float mx[8];
        #pragma unroll
        for (int h = 0; h < 2; ++h)
            #pragma unroll
            for (int nf = 0; nf < 4; ++nf) {
                const f32x4 v = sa[h][nf];
                mx[h * 4 + nf] = fmaxf(fmaxf(v[0], v[1]), fmaxf(v[2], v[3]));
            }
        const float mt_lane = fmaxf(fmaxf(fmaxf(mx[0], mx[1]), fmaxf(mx[2], mx[3])),
                                    fmaxf(fmaxf(mx[4], mx[5]), fmaxf(mx[6], mx[7])));
        if (__any(mt_lane > m_run + 8.0f)) {    // T13 gate on per-lane max
            float mt = fmaxf(mt_lane, __shfl_xor(mt_lane, 16));
            mt = fmaxf(mt, __shfl_xor(mt, 32));
            const float mn = fmaxf(m_run, mt);  // wave-uniform
            const float alpha = exp2f(m_run - mn);
            l_run *= alpha;
            #pragma unroll
            for (int nf = 0; nf < 4; ++nf)
                #pragma unroll
                for (int i = 0; i < 4; ++i)
                    o_acc[nf][i] *= alpha;
            m_run = mn;
        }
        // exp2 + tree-structured sum (8 frag-partials -> 3-level tree)
        float ps[8];
        #pragma unroll
        for (int h = 0; h < 2; ++h)
            #pragma unroll
            for (int nf = 0; nf < 4; ++nf) {
                f32x4 v = sa[h][nf];
                #pragma unroll
                for (int i = 0; i < 4; ++i) v[i] = exp2f(v[i] - m_run);
                sa[h][nf] = v;
                ps[h * 4 + nf] = (v[0] + v[1]) + (v[2] + v[3]);
            }
        float rs = ((ps[0] + ps[1]) + (ps[2] + ps[3])) +
                   ((ps[4] + ps[5]) + (ps[6] + ps[7]));
        rs += __shfl_xor(rs, 16);
        rs += __shfl_xor(rs, 32);
        l_run += rs;

        // ---- per key-half: P-pack -> pf -> PV (P buffer reused) ----
        #pragma unroll
        for (int h = 0; h < 2; ++h) {
            #pragma unroll
            for (int nf = 0; nf < 4; ++nf) {
                uint2 pv;
                pv.x = pk_bf16(sa[h][nf][0], sa[h][nf][1]);
                pv.y = pk_bf16(sa[h][nf][2], sa[h][nf][3]);
                *(uint2*)(prow + ((nf * 16 + lg * 4) ^ swz)) = pv;
            }
            short8 pf[2];
            #pragma unroll
            for (int ks = 0; ks < 2; ++ks)
                pf[ks] = *(const short8*)(prow + ((ks * 32 + lg * 8) ^ swz));

            // late ds_write of tile kt+1 (between the two PV halves)
            if (h == 0 && pfn) {
                short* Kn = (short*)Kl[cur ^ 1];
                short* Vn = (short*)Vl[cur ^ 1];
                *(short8*)(Kn + koff0) = kn0;
                *(short8*)(Kn + koff1) = kn1;
                *(short8*)(Vn + voff0) = vn0;
                *(short8*)(Vn + voff1) = vn1;
            }

            // ctx^T += V^T P^T : lane holds q=lm, d = nf*16+lg*4+i
            __builtin_amdgcn_s_setprio(1);
            #pragma unroll
            for (int nf = 0; nf < 4; ++nf) {
                const int rr = nf * 16 + lm;
                #pragma unroll
                for (int ks = 0; ks < 2; ++ks) {
                    const short8 vf = *(const short8*)(Vc + h * 4096 + rr * 64 + ((ks * 4 + lg) ^ swc) * 8);
                    o_acc[nf] = __builtin_amdgcn_mfma_f32_16x16x32_bf16(vf, pf[ks], o_acc[nf], 0, 0, 0);
                }
            }
            __builtin_amdgcn_s_setprio(0);
        }
        cur ^= 1;
    }

    // epilogue: ctx[b][q][h*64 + d] bf16, 8B vector writes
    const float inv = 1.f / l_run;
    const int b = bh >> 4, h = bh & 15;
    short* outp = Ctx + ((size_t)b * 2048 + qrow) * 1024 + h * 64 + lg * 4;
    #pragma unroll
    for (int nf = 0; nf < 4; ++nf) {
        uint2 pk;
        pk.x = pk_bf16(o_acc[nf][0] * inv, o_acc[nf][1] * inv);
        pk.y = pk_bf16(o_acc[nf][2] * inv, o_acc[nf][3] * inv);
        *(uint2*)(outp + nf * 16) = pk;
    }
}

// ---------------------------------------------------------------------------
extern "C" void kernel_launch(void* const* d_in, const int* in_sizes, int n_in,
                              void* d_out, int out_size, void* d_ws, size_t ws_size,
                              hipStream_t stream)
{
    const float* query  = (const float*)d_in[0];
    const float* key_in = (const float*)d_in[1];
    const float* value  = (const float*)d_in[2];
    const float* Wq = (const float*)d_in[3];
    const float* bq = (const float*)d_in[4];
    const float* Wk = (const float*)d_in[5];
    const float* bk = (const float*)d_in[6];
    const float* Wv = (const float*)d_in[7];
    const float* bv = (const float*)d_in[8];
    const float* Wo = (const float*)d_in[9];
    const float* bo = (const float*)d_in[10];
    float* out = (float*)d_out;

    char* ws = (char*)d_ws;
    short* Wt  = (short*)(ws);               // 4 x 2MB transposed bf16 weights
    short* Abf = (short*)(ws + (8  << 20));  // 3 x 8MB bf16 inputs (q,k,v)
    short* Qh  = (short*)(ws + (32 << 20));  // [B,H,S,64] 8MB (scaled 0.125*log2e)
    short* Kh  = (short*)(ws + (40 << 20));  // [B,H,S,64] 8MB
    short* Vt  = (short*)(ws + (48 << 20));  // [B,H,64,S] 8MB
    short* Ctx = Abf;                        // Abf dead after QKV gemm; alias

    const float qscale = 0.125f * 1.44269504088896f;  // 1/sqrt(64) * log2(e)

    hipLaunchKernelGGL(prep, dim3(10240), dim3(256), 0, stream,
                       query, key_in, value, Abf, Wq, Wk, Wv, Wo, Wt);
    hipLaunchKernelGGL(gemmqkv, dim3(8, 32, 3), dim3(256), 0, stream,
                       Abf, Wt, bq, bk, bv, Qh, Kh, Vt, qscale);
    hipLaunchKernelGGL(attn_k, dim3(16, 32), dim3(512), 0, stream,
                       Qh, Kh, Vt, Ctx);
    hipLaunchKernelGGL(gemmo, dim3(8, 64), dim3(256), 0, stream,
                       Ctx, Wt + (3 << 20), bo, out);
}

// Round 20
// 134.346 us; speedup vs baseline: 1.0359x; 1.0075x over previous
//
#include <hip/hip_runtime.h>
#include <hip/hip_bf16.h>

// Problem constants: B=2, S=2048, D=1024, H=16, HD=64, M = B*S = 4096

typedef __attribute__((ext_vector_type(8))) short short8;    // 8 bf16 = 4 VGPR
typedef __attribute__((ext_vector_type(4))) short short4v;   // 4 bf16
typedef __attribute__((ext_vector_type(4))) float f32x4;     // 16x16 C/D frag

static __device__ __forceinline__ short f2bf(float f) {
    union { float f; unsigned u; } c; c.f = f;
    unsigned r = c.u + 0x7fff + ((c.u >> 16) & 1);   // RNE
    return (short)(r >> 16);
}

// packed f32x2 -> bf16x2 (v_cvt_pk_bf16_f32)
static __device__ __forceinline__ unsigned pk_bf16(float a, float b) {
    union { __hip_bfloat162 h; unsigned u; } c;
    c.h = __float22bfloat162_rn(make_float2(a, b));
    return c.u;
}

// async global -> LDS, 16B per lane (global_load_lds_dwordx4).
typedef const void __attribute__((address_space(1)))* gas_ptr;
typedef void __attribute__((address_space(3)))* las_ptr;
static __device__ __forceinline__ void gload16(const void* g, void* l) {
    __builtin_amdgcn_global_load_lds((gas_ptr)g, (las_ptr)l, 16, 0, 0);
}

// ---------------------------------------------------------------------------
// prep: merged f32->bf16 input conversion (3 x 4M elems) + weight transpose
// (4 x W[K][N] f32 -> Wt[N][K] bf16). One dispatch, 10240 blocks. At HBM
// roofline (~96 MB @ ~6.4 TB/s ~= 15 us).
// ---------------------------------------------------------------------------
__global__ __launch_bounds__(256) void prep(
    const float* __restrict__ X0, const float* __restrict__ X1,
    const float* __restrict__ X2, short* __restrict__ Abf,
    const float* __restrict__ W0, const float* __restrict__ W1,
    const float* __restrict__ W2, const float* __restrict__ W3,
    short* __restrict__ Wt)
{
    __shared__ float tile[32][33];
    const int bid = blockIdx.x;
    if (bid < 6144) {           // --- tobf16: 2048 blocks per input ---
        const int zz = bid >> 11, xb = bid & 2047;
        const float* X = zz == 0 ? X0 : zz == 1 ? X1 : X2;
        short* o = Abf + ((size_t)zz << 22);
        const int i = (xb * 256 + threadIdx.x) * 8;
        const float4 a = *(const float4*)(X + i);
        const float4 b = *(const float4*)(X + i + 4);
        uint4 r;
        r.x = pk_bf16(a.x, a.y); r.y = pk_bf16(a.z, a.w);
        r.z = pk_bf16(b.x, b.y); r.w = pk_bf16(b.z, b.w);
        *(uint4*)(o + i) = r;
    } else {                    // --- wtrans: 1024 blocks per weight ---
        const int wid = bid - 6144;
        const int z = wid >> 10;
        const float* W = z == 0 ? W0 : z == 1 ? W1 : z == 2 ? W2 : W3;
        short* O = Wt + ((size_t)z << 20);
        const int k0 = (wid & 31) * 32, n0 = ((wid >> 5) & 31) * 32;
        const int tx = threadIdx.x & 31, ty = threadIdx.x >> 5;  // (32,8)
        #pragma unroll
        for (int j = 0; j < 32; j += 8)
            tile[ty + j][tx] = W[(k0 + ty + j) * 1024 + n0 + tx];
        __syncthreads();
        #pragma unroll
        for (int j = 0; j < 32; j += 8)
            O[(n0 + ty + j) * 1024 + k0 + tx] = f2bf(tile[tx][ty + j]);
    }
}

// ---------------------------------------------------------------------------
// Merged Q/K/V projection GEMM — m97 128x128 structure (banked best):
// BM=BN=128, BK=32, 4 waves x (64x64 quadrant, acc[4][4] of 16x16x32).
// Both operands bf16 staged via global_load_lds dwordx4, double-buffered,
// 1 barrier/K-step. Grid (8,32,3) = 768 blocks = 3/CU; T1 bijective XCD
// swizzle. (BK=64 NOT applied here: 64KB LDS would drop 3->2 blocks/CU —
// the m132 regression regime.)
// ---------------------------------------------------------------------------
__global__ __launch_bounds__(256, 3) void gemmqkv(
    const short* __restrict__ Abase, const short* __restrict__ Wt,
    const float* __restrict__ bq, const float* __restrict__ bk,
    const float* __restrict__ bv, short* __restrict__ Qh,
    short* __restrict__ Kh, short* __restrict__ Vt, float qscale)
{
    __shared__ short Al[2][4096];   // [128 m][32 k]
    __shared__ short Bl[2][4096];   // [128 n][32 k]
    const int flat = blockIdx.z * 256 + blockIdx.y * 8 + blockIdx.x;
    const int remap = (flat & 7) * 96 + (flat >> 3);   // 768 % 8 == 0: bijective
    const int z = remap >> 8;
    const int rem = remap & 255;
    const int m0 = (rem >> 3) * 128, n0 = (rem & 7) * 128;

    const short* Aa = Abase + ((size_t)z << 22);
    const short* Ba = Wt + ((size_t)z << 20);
    const float* bias = z == 0 ? bq : z == 1 ? bk : bv;
    short* O = z == 0 ? Qh : z == 1 ? Kh : Vt;
    const float scale = z == 0 ? qscale : 1.0f;

    const int t = threadIdx.x;
    const int lane = t & 63, w = t >> 6;
    const int lm = lane & 15, lg = lane >> 4;
    const int wr = w >> 1, wc = w & 1;

    #define STAGEQ(buf, k0) do {                                              \
        _Pragma("unroll")                                                     \
        for (int j = 0; j < 2; ++j) {                                         \
            const int c = j * 256 + t;                                        \
            gload16(Aa + (size_t)(m0 + (c >> 2)) * 1024 + (k0) + (c & 3) * 8, \
                    &Al[buf][j * 2048 + w * 512]);                            \
            gload16(Ba + (size_t)(n0 + (c >> 2)) * 1024 + (k0) + (c & 3) * 8, \
                    &Bl[buf][j * 2048 + w * 512]);                            \
        }                                                                     \
    } while (0)

    f32x4 acc[4][4] = {};
    STAGEQ(0, 0);
    __syncthreads();

    int buf = 0;
    for (int kk = 0; kk < 32; ++kk) {
        if (kk < 31) STAGEQ(buf ^ 1, (kk + 1) * 32);
        const short* Ab = Al[buf];
        const short* Bb = Bl[buf];
        short8 af[4], bfr[4];
        #pragma unroll
        for (int mf = 0; mf < 4; ++mf)
            af[mf] = *(const short8*)(Ab + (wr * 64 + mf * 16 + lm) * 32 + lg * 8);
        #pragma unroll
        for (int nf = 0; nf < 4; ++nf)
            bfr[nf] = *(const short8*)(Bb + (wc * 64 + nf * 16 + lm) * 32 + lg * 8);
        #pragma unroll
        for (int mf = 0; mf < 4; ++mf)
            #pragma unroll
            for (int nf = 0; nf < 4; ++nf)
                acc[mf][nf] = __builtin_amdgcn_mfma_f32_16x16x32_bf16(
                    af[mf], bfr[nf], acc[mf][nf], 0, 0, 0);
        __syncthreads();
        buf ^= 1;
    }
    #undef STAGEQ

    // epilogue — D frag: col = lm (n), rows = lg*4 + i (m)
    #pragma unroll
    for (int mf = 0; mf < 4; ++mf) {
        const int mb = m0 + wr * 64 + mf * 16 + lg * 4;
        #pragma unroll
        for (int nf = 0; nf < 4; ++nf) {
            const int n = n0 + wc * 64 + nf * 16 + lm;
            const float bs = bias[n];
            if (z == 2) {   // V^T [B,H,64,S]: 4 consecutive s per lane
                short4v sv;
                #pragma unroll
                for (int i = 0; i < 4; ++i)
                    sv[i] = f2bf(acc[mf][nf][i] + bs);
                const int addr = (((mb >> 11) * 16 + (n >> 6)) * 64 + (n & 63)) * 2048 + (mb & 2047);
                *(short4v*)&O[addr] = sv;
            } else {        // head-split [B,H,S,64]
                #pragma unroll
                for (int i = 0; i < 4; ++i) {
                    const int m = mb + i;
                    const int addr = (((m >> 11) * 16 + (n >> 6)) * 2048 + (m & 2047)) * 64 + (n & 63);
                    O[addr] = f2bf(scale * (acc[mf][nf][i] + bs));
                }
            }
        }
    }
}

// ---------------------------------------------------------------------------
// Final projection v3: out = Ctx @ Wo^T + bo, f32 flat.
// BM=64, BN=64, BK=64 — grid (16,64) = 1024 blocks = 4 blocks/CU (was 512 =
// 2/CU, latency-starved at 8 waves/CU; r4/r16 lesson: grid parallelism is
// the dominant lever for this 2-phase structure). LDS 32KB fits 4/CU.
// 4 waves each own a 32x32 quadrant (acc[2][2], 8 MFMA/barrier, BK=64 keeps
// barriers at 16). rule-21c swizzle combo kept: gload16 LINEAR dest +
// pre-swizzled global source (kc ^= row&7) + same XOR on frag read.
// T1 XCD remap (1024 % 8 == 0: bijective).
// ---------------------------------------------------------------------------
__global__ __launch_bounds__(256) void gemmo(
    const short* __restrict__ Aa, const short* __restrict__ Ba,
    const float* __restrict__ bias, float* __restrict__ Out)
{
    __shared__ short Al[2][4096];   // [64 m][64 k], source-swizzled
    __shared__ short Bl[2][4096];   // [64 n][64 k], source-swizzled
    const int flat = blockIdx.y * 16 + blockIdx.x;
    const int remap = (flat & 7) * 128 + (flat >> 3);   // 1024 % 8 == 0: bijective
    const int m0 = (remap >> 4) * 64, n0 = (remap & 15) * 64;

    const int t = threadIdx.x;
    const int lane = t & 63, w = t >> 6;
    const int lm = lane & 15, lg = lane >> 4;
    const int wr = w >> 1, wc = w & 1;
    const int sw = lm & 7;          // frag-read chunk swizzle (row&7 == lm&7)

    // staging: A and B each 512 chunks (2/thread each); LDS dest linear c*8;
    // global source k-chunk = (c&7) ^ (row&7), row = c>>3.
    #define STAGEO(buf, k0) do {                                              \
        _Pragma("unroll")                                                     \
        for (int j = 0; j < 2; ++j) {                                         \
            const int c = j * 256 + t;                                        \
            gload16(Aa + (size_t)(m0 + (c >> 3)) * 1024 + (k0)                \
                        + (((c & 7) ^ ((c >> 3) & 7)) * 8),                   \
                    &Al[buf][j * 2048 + t * 8]);                              \
            gload16(Ba + (size_t)(n0 + (c >> 3)) * 1024 + (k0)                \
                        + (((c & 7) ^ ((c >> 3) & 7)) * 8),                   \
                    &Bl[buf][j * 2048 + t * 8]);                              \
        }                                                                     \
    } while (0)

    f32x4 acc[2][2] = {};
    STAGEO(0, 0);
    __syncthreads();

    int buf = 0;
    for (int kk = 0; kk < 16; ++kk) {
        if (kk < 15) STAGEO(buf ^ 1, (kk + 1) * 64);
        const short* Ab = Al[buf];
        const short* Bb = Bl[buf];
        #pragma unroll
        for (int ks = 0; ks < 2; ++ks) {
            short8 af[2], bfr[2];
            #pragma unroll
            for (int mf = 0; mf < 2; ++mf)
                af[mf] = *(const short8*)(Ab + (wr * 32 + mf * 16 + lm) * 64
                                             + (((ks * 4 + lg) ^ sw) * 8));
            #pragma unroll
            for (int nf = 0; nf < 2; ++nf)
                bfr[nf] = *(const short8*)(Bb + (wc * 32 + nf * 16 + lm) * 64
                                              + (((ks * 4 + lg) ^ sw) * 8));
            #pragma unroll
            for (int mf = 0; mf < 2; ++mf)
                #pragma unroll
                for (int nf = 0; nf < 2; ++nf)
                    acc[mf][nf] = __builtin_amdgcn_mfma_f32_16x16x32_bf16(
                        af[mf], bfr[nf], acc[mf][nf], 0, 0, 0);
        }
        __syncthreads();
        buf ^= 1;
    }
    #undef STAGEO

    #pragma unroll
    for (int mf = 0; mf < 2; ++mf) {
        const int mb = m0 + wr * 32 + mf * 16 + lg * 4;
        #pragma unroll
        for (int nf = 0; nf < 2; ++nf) {
            const int n = n0 + wc * 32 + nf * 16 + lm;
            const float bs = bias[n];
            #pragma unroll
            for (int i = 0; i < 4; ++i)
                Out[(mb + i) * 1024 + n] = acc[mf][nf][i] + bs;
        }
    }
}

// ---------------------------------------------------------------------------
// Flash attention v14 (banked best, ~72 µs): 8 waves x 16 q-rows, KVBLK=128,
// V tile as two [64][64] halves, XOR chunk swizzle, double-buffer + T14,
// 1 barrier/tile, swapped QK^T/PV, exp2 softmax, lazy-max T13 (per-lane gate,
// shuffles only in rescale branch), tree reductions, XCD-chunked remap.
// ---------------------------------------------------------------------------
__global__ __launch_bounds__(512, 4) void attn_k(
    const short* __restrict__ Q, const short* __restrict__ K,
    const short* __restrict__ V, short* __restrict__ Ctx)
{
    __shared__ short Kl[2][128][64];
    __shared__ short Vl[2][2][64][64];   // [buf][key-half][d-row][key-chunk]
    __shared__ short Pl[8][16][64];
    const int t = threadIdx.x;
    const int flat = blockIdx.y * 16 + blockIdx.x;
    const int remap = (flat & 7) * 64 + (flat >> 3);   // 512 % 8 == 0: bijective
    const int qt = remap & 15, bh = remap >> 4;        // XCD c -> bh in [4c,4c+4)
    const int lane = t & 63, w = t >> 6;   // 8 waves
    const int lm = lane & 15, lg = lane >> 4;
    const int swz = (lm & 7) << 3;          // P-buffer swizzle (shorts)
    const int swc = lm & 7;                 // K/V read chunk swizzle

    const int qrow = qt * 128 + w * 16 + lm;
    short8 qf[2];
    #pragma unroll
    for (int ks = 0; ks < 2; ++ks)
        qf[ks] = *(const short8*)(Q + ((size_t)bh * 2048 + qrow) * 64 + ks * 32 + lg * 8);

    float m_run = -3e38f, l_run = 0.f;
    f32x4 o_acc[4] = {};

    const int rk = t >> 2, ck = t & 3;
    const int rv = t >> 3, cv = t & 7;
    const short* Kg = K + ((size_t)bh * 2048 + rk) * 64 + ck * 16;
    const short* Vg = V + ((size_t)bh * 64 + rv) * 2048 + cv * 16;
    const int koff0 = rk * 64 + ((ck * 2) ^ (rk & 7)) * 8;
    const int koff1 = rk * 64 + ((ck * 2 + 1) ^ (rk & 7)) * 8;
    const int vhalf = (cv >> 2) * 4096;
    const int voff0 = vhalf + rv * 64 + (((cv * 2) & 7) ^ (rv & 7)) * 8;
    const int voff1 = vhalf + rv * 64 + (((cv * 2 + 1) & 7) ^ (rv & 7)) * 8;

    {   // prologue: stage tile 0 into buffer 0
        short8 a = *(const short8*)(Kg);
        short8 b = *(const short8*)(Kg + 8);
        short8 c = *(const short8*)(Vg);
        short8 d = *(const short8*)(Vg + 8);
        *(short8*)((short*)Kl[0] + koff0) = a;
        *(short8*)((short*)Kl[0] + koff1) = b;
        *(short8*)((short*)Vl[0] + voff0) = c;
        *(short8*)((short*)Vl[0] + voff1) = d;
    }

    short* prow = &Pl[w][lm][0];
    int cur = 0;

    for (int kt = 0; kt < 16; ++kt) {
        __syncthreads();   // stage[cur] visible; [cur^1] free for writing

        // early-issue global loads for tile kt+1 (T14)
        short8 kn0, kn1, vn0, vn1;
        const bool pfn = (kt < 15);
        if (pfn) {
            const short* Kgn = Kg + (size_t)(kt + 1) * 8192;   // 128 rows * 64
            const short* Vgn = Vg + (kt + 1) * 128;
            kn0 = *(const short8*)(Kgn);
            kn1 = *(const short8*)(Kgn + 8);
            vn0 = *(const short8*)(Vgn);
            vn1 = *(const short8*)(Vgn + 8);
        }

        const short* Kc = (const short*)Kl[cur];
        const short* Vc = (const short*)Vl[cur];

        // ---- S^T = K Q^T, BOTH halves: lane holds q=lm, 32 key-vals ----
        f32x4 sa[2][4] = {};
        __builtin_amdgcn_s_setprio(1);
        #pragma unroll
        for (int h = 0; h < 2; ++h)
            #pragma unroll
            for (int nf = 0; nf < 4; ++nf) {
                const int rr = h * 64 + nf * 16 + lm;
                #pragma unroll
                for (int ks = 0; ks < 2; ++ks) {
                    const short8 kf = *(const short8*)(Kc + rr * 64 + ((ks * 4 + lg) ^ swc) * 8);
                    sa[h][nf] = __builtin_amdgcn_mfma_f32_16x16x32_bf16(kf, qf[ks], sa[h][nf], 0, 0, 0);
                }
            }
        __builtin_amdgcn_s_setprio(0);

        // ---- per-lane max (tree, no shuffles in the common path) ----
        float mx[8];
        #pragma unroll
        for (int h = 0; h < 2; ++h)
            #pragma unroll
            for (int nf = 0; nf < 4; ++nf) {
                const f32x4 v = sa[h][nf];
                mx[h * 4 + nf] = fmaxf(fmaxf(v[0], v[1]), fmaxf(v[2], v[3]));
            }
        const float mt_lane = fmaxf(fmaxf(fmaxf(mx[0], mx[1]), fmaxf(mx[2], mx[3])),
                                    fmaxf(fmaxf(mx[4], mx[5]), fmaxf(mx[6], mx[7])));
        if (__any(mt_lane > m_run + 8.0f)) {    // T13 gate on per-lane max
            float mt = fmaxf(mt_lane, __shfl_xor(mt_lane, 16));
            mt = fmaxf(mt, __shfl_xor(mt, 32));
            const float mn = fmaxf(m_run, mt);  // wave-uniform
            const float alpha = exp2f(m_run - mn);
            l_run *= alpha;
            #pragma unroll
            for (int nf = 0; nf < 4; ++nf)
                #pragma unroll
                for (int i = 0; i < 4; ++i)
                    o_acc[nf][i] *= alpha;
            m_run = mn;
        }
        // exp2 + tree-structured sum (8 frag-partials -> 3-level tree)
        float ps[8];
        #pragma unroll
        for (int h = 0; h < 2; ++h)
            #pragma unroll
            for (int nf = 0; nf < 4; ++nf) {
                f32x4 v = sa[h][nf];
                #pragma unroll
                for (int i = 0; i < 4; ++i) v[i] = exp2f(v[i] - m_run);
                sa[h][nf] = v;
                ps[h * 4 + nf] = (v[0] + v[1]) + (v[2] + v[3]);
            }
        float rs = ((ps[0] + ps[1]) + (ps[2] + ps[3])) +
                   ((ps[4] + ps[5]) + (ps[6] + ps[7]));
        rs += __shfl_xor(rs, 16);
        rs += __shfl_xor(rs, 32);
        l_run += rs;

        // ---- per key-half: P-pack -> pf -> PV (P buffer reused) ----
        #pragma unroll
        for (int h = 0; h < 2; ++h) {
            #pragma unroll
            for (int nf = 0; nf < 4; ++nf) {
                uint2 pv;
                pv.x = pk_bf16(sa[h][nf][0], sa[h][nf][1]);
                pv.y = pk_bf16(sa[h][nf][2], sa[h][nf][3]);
                *(uint2*)(prow + ((nf * 16 + lg * 4) ^ swz)) = pv;
            }
            short8 pf[2];
            #pragma unroll
            for (int ks = 0; ks < 2; ++ks)
                pf[ks] = *(const short8*)(prow + ((ks * 32 + lg * 8) ^ swz));

            // late ds_write of tile kt+1 (between the two PV halves)
            if (h == 0 && pfn) {
                short* Kn = (short*)Kl[cur ^ 1];
                short* Vn = (short*)Vl[cur ^ 1];
                *(short8*)(Kn + koff0) = kn0;
                *(short8*)(Kn + koff1) = kn1;
                *(short8*)(Vn + voff0) = vn0;
                *(short8*)(Vn + voff1) = vn1;
            }

            // ctx^T += V^T P^T : lane holds q=lm, d = nf*16+lg*4+i
            __builtin_amdgcn_s_setprio(1);
            #pragma unroll
            for (int nf = 0; nf < 4; ++nf) {
                const int rr = nf * 16 + lm;
                #pragma unroll
                for (int ks = 0; ks < 2; ++ks) {
                    const short8 vf = *(const short8*)(Vc + h * 4096 + rr * 64 + ((ks * 4 + lg) ^ swc) * 8);
                    o_acc[nf] = __builtin_amdgcn_mfma_f32_16x16x32_bf16(vf, pf[ks], o_acc[nf], 0, 0, 0);
                }
            }
            __builtin_amdgcn_s_setprio(0);
        }
        cur ^= 1;
    }

    // epilogue: ctx[b][q][h*64 + d] bf16, 8B vector writes
    const float inv = 1.f / l_run;
    const int b = bh >> 4, h = bh & 15;
    short* outp = Ctx + ((size_t)b * 2048 + qrow) * 1024 + h * 64 + lg * 4;
    #pragma unroll
    for (int nf = 0; nf < 4; ++nf) {
        uint2 pk;
        pk.x = pk_bf16(o_acc[nf][0] * inv, o_acc[nf][1] * inv);
        pk.y = pk_bf16(o_acc[nf][2] * inv, o_acc[nf][3] * inv);
        *(uint2*)(outp + nf * 16) = pk;
    }
}

// ---------------------------------------------------------------------------
extern "C" void kernel_launch(void* const* d_in, const int* in_sizes, int n_in,
                              void* d_out, int out_size, void* d_ws, size_t ws_size,
                              hipStream_t stream)
{
    const float* query  = (const float*)d_in[0];
    const float* key_in = (const float*)d_in[1];
    const float* value  = (const float*)d_in[2];
    const float* Wq = (const float*)d_in[3];
    const float* bq = (const float*)d_in[4];
    const float* Wk = (const float*)d_in[5];
    const float* bk = (const float*)d_in[6];
    const float* Wv = (const float*)d_in[7];
    const float* bv = (const float*)d_in[8];
    const float* Wo = (const float*)d_in[9];
    const float* bo = (const float*)d_in[10];
    float* out = (float*)d_out;

    char* ws = (char*)d_ws;
    short* Wt  = (short*)(ws);               // 4 x 2MB transposed bf16 weights
    short* Abf = (short*)(ws + (8  << 20));  // 3 x 8MB bf16 inputs (q,k,v)
    short* Qh  = (short*)(ws + (32 << 20));  // [B,H,S,64] 8MB (scaled 0.125*log2e)
    short* Kh  = (short*)(ws + (40 << 20));  // [B,H,S,64] 8MB
    short* Vt  = (short*)(ws + (48 << 20));  // [B,H,64,S] 8MB
    short* Ctx = Abf;                        // Abf dead after QKV gemm; alias

    const float qscale = 0.125f * 1.44269504088896f;  // 1/sqrt(64) * log2(e)

    hipLaunchKernelGGL(prep, dim3(10240), dim3(256), 0, stream,
                       query, key_in, value, Abf, Wq, Wk, Wv, Wo, Wt);
    hipLaunchKernelGGL(gemmqkv, dim3(8, 32, 3), dim3(256), 0, stream,
                       Abf, Wt, bq, bk, bv, Qh, Kh, Vt, qscale);
    hipLaunchKernelGGL(attn_k, dim3(16, 32), dim3(512), 0, stream,
                       Qh, Kh, Vt, Ctx);
    hipLaunchKernelGGL(gemmo, dim3(16, 64), dim3(256), 0, stream,
                       Ctx, Wt + (3 << 20), bo, out);
}